// Round 1
// baseline (66.342 us; speedup 1.0000x reference)
//
#include <hip/hip_runtime.h>

#define T_LEN 2400
#define LPC_N 16
#define FRAME 160
#define OPT   8                    // outputs per thread (divides FRAME -> no frame straddle)
#define GPROW (T_LEN / OPT)        // 300 groups per batch row
#define BLOCK 256

typedef float f4 __attribute__((ext_vector_type(4)));

// sig: (B, 2400, 1) f32 in [0,255); lpc: (B, 15, 16) f32; out: (B, 2400, 1) f32
__global__ __launch_bounds__(BLOCK)
void diff_pred_26319559589961_kernel(const float* __restrict__ sig,
                                     const float* __restrict__ lpc,
                                     float* __restrict__ out,
                                     int total_groups)
{
    const int g = blockIdx.x * BLOCK + threadIdx.x;
    if (g >= total_groups) return;

    const int b     = g / GPROW;           // magic-mul division
    const int gi    = g - b * GPROW;       // group within row, [0, 300)
    const int t     = gi * OPT;            // output start sample
    const int frame = gi / (FRAME / OPT);  // gi / 20, [0, 15)

    const float* srow = sig + (size_t)b * T_LEN;

    // ---- decode xt[t-16 .. t+7] into registers (mu-law -> linear) ----
    // u2l(v) = copysign((32768/255) * (2^(|v-128|/16) - 1), v-128)
    // Reference zero-pads the *decoded* history, so invalid vectors are 0.0f.
    // ts is always a multiple of 4, so each float4 is entirely valid or entirely padded.
    float x[LPC_N + OPT];
    #pragma unroll
    for (int j = 0; j < (LPC_N + OPT) / 4; ++j) {
        const int ts = t - LPC_N + 4 * j;
        float4 r = make_float4(0.0f, 0.0f, 0.0f, 0.0f);
        if (ts >= 0) {
            const float4 v = *(const float4*)(srow + ts);
            const float ux = v.x - 128.0f, uy = v.y - 128.0f,
                        uz = v.z - 128.0f, uw = v.w - 128.0f;
            r.x = copysignf((32768.0f/255.0f) * (exp2f(fabsf(ux) * 0.0625f) - 1.0f), ux);
            r.y = copysignf((32768.0f/255.0f) * (exp2f(fabsf(uy) * 0.0625f) - 1.0f), uy);
            r.z = copysignf((32768.0f/255.0f) * (exp2f(fabsf(uz) * 0.0625f) - 1.0f), uz);
            r.w = copysignf((32768.0f/255.0f) * (exp2f(fabsf(uw) * 0.0625f) - 1.0f), uw);
        }
        x[4 * j + 0] = r.x;
        x[4 * j + 1] = r.y;
        x[4 * j + 2] = r.z;
        x[4 * j + 3] = r.w;
    }

    // ---- per-frame LPC coeffs (broadcast across 20 consecutive lanes, L1-served) ----
    const float4* c = (const float4*)(lpc + ((size_t)b * 15 + frame) * LPC_N);
    const float4 c0 = c[0], c1 = c[1], c2 = c[2], c3 = c[3];
    const float cf[16] = { c0.x, c0.y, c0.z, c0.w,
                           c1.x, c1.y, c1.z, c1.w,
                           c2.x, c2.y, c2.z, c2.w,
                           c3.x, c3.y, c3.z, c3.w };

    // ---- 8 outputs: pred[t+k] = -sum_i cf[i] * xt[t+k-i]; then l2u encode ----
    float o[OPT];
    #pragma unroll
    for (int k = 0; k < OPT; ++k) {
        float acc = 0.0f;
        #pragma unroll
        for (int i = 0; i < LPC_N; ++i)
            acc += cf[i] * x[LPC_N + k - i];
        const float pred = -acc;
        // l2u(p) = clip(128 + copysign(16*log2(1 + (255/32768)|p|), p), 0, 255)
        const float u = copysignf(
            16.0f * __log2f(1.0f + (255.0f/32768.0f) * fabsf(pred)), pred);
        o[k] = fminf(fmaxf(128.0f + u, 0.0f), 255.0f);
    }

    // ---- store 32B per thread, nontemporal (output is never re-read) ----
    float* dst = out + (size_t)b * T_LEN + t;
    f4 o0 = { o[0], o[1], o[2], o[3] };
    f4 o1 = { o[4], o[5], o[6], o[7] };
    __builtin_nontemporal_store(o0, (f4*)dst);
    __builtin_nontemporal_store(o1, (f4*)(dst + 4));
}

extern "C" void kernel_launch(void* const* d_in, const int* in_sizes, int n_in,
                              void* d_out, int out_size, void* d_ws, size_t ws_size,
                              hipStream_t stream) {
    const float* sig = (const float*)d_in[0];   // (B, 2400, 1)
    const float* lpc = (const float*)d_in[1];   // (B, 15, 16)
    float* out = (float*)d_out;                 // (B, 2400, 1)

    const int B = in_sizes[0] / T_LEN;
    const int total_groups = B * GPROW;                  // 307200 for B=1024
    const int nblk = (total_groups + BLOCK - 1) / BLOCK; // 1200
    diff_pred_26319559589961_kernel<<<dim3(nblk), dim3(BLOCK), 0, stream>>>(
        sig, lpc, out, total_groups);
}